// Round 2
// baseline (402.008 us; speedup 1.0000x reference)
//
#include <hip/hip_runtime.h>

#define S_LEN 4096
#define NT 512
#define PER 8
#define RANK 8
#define AP 4160   // padded LDS array size (max transpose addr 4151)
#define TWO_PI 6.2831853071795864769f

__device__ __forceinline__ void cmul(float& xr, float& xi, float cr, float ci){
    float tr = xr*cr - xi*ci;
    xi = xr*ci + xi*cr;
    xr = tr;
}

// 4-point DFT, in place. SIGN=-1 forward (W=e^{-i}), SIGN=+1 inverse.
// Natural-order outputs: slots (a,b,c,d) = X[0..3].
template<int SIGN>
__device__ __forceinline__ void dft4(float& ar,float& ai,float& br,float& bi,
                                     float& cr,float& ci,float& dr,float& di){
    float Ar=ar+cr, Ai=ai+ci;
    float Br=ar-cr, Bi=ai-ci;
    float Cr=br+dr, Ci=bi+di;
    float Dr, Di;
    if (SIGN < 0){ Dr = bi-di; Di = dr-br; }   // -i*(b-d)
    else         { Dr = di-bi; Di = br-dr; }   // +i*(b-d)
    ar=Ar+Cr; ai=Ai+Ci;
    br=Br+Dr; bi=Bi+Di;
    cr=Ar-Cr; ci=Ai-Ci;
    dr=Br-Dr; di=Bi-Di;
}

// 8-point DFT in registers, natural-order in AND out (even/odd radix-2 split).
template<int SIGN>
__device__ __forceinline__ void dft8(float ur[8], float ui[8]){
    const float h = 0.70710678118654752f;
    float er0=ur[0], ei0=ui[0], er1=ur[2], ei1=ui[2];
    float er2=ur[4], ei2=ui[4], er3=ur[6], ei3=ui[6];
    float fr0=ur[1], fi0=ui[1], fr1=ur[3], fi1=ui[3];
    float fr2=ur[5], fi2=ui[5], fr3=ur[7], fi3=ui[7];
    dft4<SIGN>(er0,ei0, er1,ei1, er2,ei2, er3,ei3);   // E = DFT4(x0,x2,x4,x6)
    dft4<SIGN>(fr0,fi0, fr1,fi1, fr2,fi2, fr3,fi3);   // O = DFT4(x1,x3,x5,x7)
    // O[k] *= W8^k
    {   const float c =  h, s_ = (SIGN<0) ? -h : h;
        cmul(fr1, fi1, c, s_); }
    {   float tr = fr2, ti = fi2;
        if (SIGN < 0){ fr2 =  ti; fi2 = -tr; }   // *(-i)
        else         { fr2 = -ti; fi2 =  tr; }   // *(+i)
    }
    {   const float c = -h, s_ = (SIGN<0) ? -h : h;
        cmul(fr3, fi3, c, s_); }
    ur[0]=er0+fr0; ui[0]=ei0+fi0;
    ur[1]=er1+fr1; ui[1]=ei1+fi1;
    ur[2]=er2+fr2; ui[2]=ei2+fi2;
    ur[3]=er3+fr3; ui[3]=ei3+fi3;
    ur[4]=er0-fr0; ui[4]=ei0-fi0;
    ur[5]=er1-fr1; ui[5]=ei1-fi1;
    ur[6]=er2-fr2; ui[6]=ei2-fi2;
    ur[7]=er3-fr3; ui[7]=ei3-fi3;
}

// multiply u[m] by exp(SIGN * i * theta * m), m = 0..7 (iterative powers)
template<int SIGN>
__device__ __forceinline__ void twiddle8(float ur[8], float ui[8], float theta){
    float s, c;
    __sincosf(theta, &s, &c);
    const float wi = (SIGN < 0) ? -s : s;
    const float wr = c;
    float pr = wr, pi = wi;      // w^1
    cmul(ur[1], ui[1], pr, pi);
#pragma unroll
    for (int m=2;m<8;m++){
        float nr = pr*wr - pi*wi;
        pi = pr*wi + pi*wr;
        pr = nr;
        cmul(ur[m], ui[m], pr, pi);
    }
}

// 4096 = 8*8*8*8, n = n1 + 8n2 + 64n3 + 512n4, k = e1 + 8e2 + 64e3 + 512e4.
// Round r DFTs over n_{5-r}; twiddles W_{8^r}^{digit * k_so_far}.
// LDS layouts are digit-reversed so every round's READ is linear:
//   A[n1+8n2 + 64e1 + 512n3]           (write: 2-way, free; read: t+512m)
//   B[n1 + 8e1 + 64e2 + 520n2]         (write: 2-way via pad 520; read: t+520m)
//   C[(e1+8e2) + 64e3 + 520n1]         (write: 2-way via pad 520; read: t+520m)
//   z linear [t + 512e4]

__global__ __launch_bounds__(NT, 8) void recip_mixer(
    const float* __restrict__ x,
    const float* __restrict__ Ur, const float* __restrict__ Ui,
    const float* __restrict__ Vr, const float* __restrict__ Vi,
    const float* __restrict__ Wr, const float* __restrict__ Wi,
    const float* __restrict__ P1w, const float* __restrict__ P1b,
    const float* __restrict__ P2w, const float* __restrict__ P2b,
    const float* __restrict__ alphap,
    float* __restrict__ out)
{
    __shared__ float sre[AP], sim[AP];
    __shared__ float red[256];
    __shared__ float hid[RANK];
    __shared__ float gam[2 * RANK];

    const int t    = threadIdx.x;
    const int row  = blockIdx.x;
    const int lane = t & 63;
    const int wid  = t >> 6;

    float ur[8], ui[8];

    // ================= forward FFT: natural in -> natural k out =================
    {
        // round 1: t = n1+8n2+64n3; DFT over n4 (global reads coalesced)
        const float* xrow = x + (size_t)row * S_LEN;
#pragma unroll
        for (int c=0;c<8;c++){ ur[c] = xrow[t + 512*c]; ui[c] = 0.0f; }
        dft8<-1>(ur, ui);
        const int baseA = (t & 63) + 512 * (t >> 6);
#pragma unroll
        for (int e=0;e<8;e++){ sre[baseA + 64*e] = ur[e]; sim[baseA + 64*e] = ui[e]; }
    }
    __syncthreads();
    {
        // round 2: t = (n1+8n2) + 64e1; read A linear, twiddle W_64^{n3 e1}, DFT over n3
#pragma unroll
        for (int m=0;m<8;m++){ ur[m] = sre[t + 512*m]; ui[m] = sim[t + 512*m]; }
        twiddle8<-1>(ur, ui, TWO_PI * (float)(t >> 6) * (1.0f/64.0f));
        dft8<-1>(ur, ui);
        __syncthreads();   // all of A consumed before B overwrites
        const int baseB = (t & 7) + 8*(t >> 6) + 520*((t >> 3) & 7);
#pragma unroll
        for (int e=0;e<8;e++){ sre[baseB + 64*e] = ur[e]; sim[baseB + 64*e] = ui[e]; }
    }
    __syncthreads();
    {
        // round 3: t = n1 + 8e1 + 64e2; read B linear, twiddle W_512^{n2 (e1+8e2)}, DFT over n2
#pragma unroll
        for (int m=0;m<8;m++){ ur[m] = sre[t + 520*m]; ui[m] = sim[t + 520*m]; }
        twiddle8<-1>(ur, ui, TWO_PI * (float)(t >> 3) * (1.0f/512.0f));
        dft8<-1>(ur, ui);
        __syncthreads();   // B consumed before C overwrites
        const int baseC = (t >> 3) + 520*(t & 7);
#pragma unroll
        for (int e=0;e<8;e++){ sre[baseC + 64*e] = ur[e]; sim[baseC + 64*e] = ui[e]; }
    }
    __syncthreads();
    {
        // round 4: t = e1+8e2+64e3 = k mod 512; read C linear, twiddle W_4096^{n1 t}, DFT over n1
#pragma unroll
        for (int m=0;m<8;m++){ ur[m] = sre[t + 520*m]; ui[m] = sim[t + 520*m]; }
        twiddle8<-1>(ur, ui, TWO_PI * (float)t * (1.0f/4096.0f));
        dft8<-1>(ur, ui);
        __syncthreads();   // C consumed before z overwrites
        // write spectrum linear: z[t + 512*e4]
#pragma unroll
        for (int e=0;e<8;e++){ sre[t + 512*e] = ur[e]; sim[t + 512*e] = ui[e]; }
    }
    __syncthreads();

    // ================= middle phase (z in sre/sim linear) =====
    // phase 1: hidden = relu(P1w @ [Re z ; Im z] + P1b)
    {
        float h[RANK];
#pragma unroll
        for (int r = 0; r < RANK; r++) h[r] = 0.0f;
        for (int i = 0; i < PER; i++) {
            int k = t + NT * i;
            float zr = sre[k], zi = sim[k];
#pragma unroll
            for (int r = 0; r < RANK; r++) {
                h[r] += zr * P1w[r * (2 * S_LEN) + k]
                      + zi * P1w[r * (2 * S_LEN) + S_LEN + k];
            }
        }
#pragma unroll
        for (int r = 0; r < RANK; r++) {
#pragma unroll
            for (int off = 32; off > 0; off >>= 1)
                h[r] += __shfl_xor(h[r], off, 64);
        }
        if (lane == 0) {
#pragma unroll
            for (int r = 0; r < RANK; r++) red[wid * RANK + r] = h[r];
        }
        __syncthreads();
        if (t < RANK) {
            float v = 0.0f;
#pragma unroll
            for (int w = 0; w < 8; w++) v += red[w * RANK + t];
            hid[t] = fmaxf(v + P1b[t], 0.0f);
        }
        __syncthreads();
    }

    // phase 2+3: per-k gain, scale z, accumulate p/q rank-8 partials
    {
        float hh[RANK];
#pragma unroll
        for (int r = 0; r < RANK; r++) hh[r] = hid[r];
        const float alpha = alphap[0];

        float pr[RANK], pim[RANK], qr[RANK], qim[RANK];
#pragma unroll
        for (int r = 0; r < RANK; r++) { pr[r]=0.f; pim[r]=0.f; qr[r]=0.f; qim[r]=0.f; }

        for (int i = 0; i < PER; i++) {
            int k = t + NT * i;
            int m = (k < S_LEN - k) ? k : (S_LEN - k);
            float nf = (float)(2 * m) * (1.0f / (float)S_LEN);
            float tt = nf * 5.0f;
            float lb = __expf(-0.5f * tt * tt);
            float hd = 0.5f / (1.0f + __expf(-(nf - 0.6f) * 10.0f));
            float bg = fmaxf(1.0f + lb - hd, 0.0f);

            float scaled = nf * 4095.0f;
            float fl  = floorf(scaled);
            int   lo  = (int)fl;
            int   hi  = (int)ceilf(scaled);
            float fr  = scaled - fl;

            const float4* p2lo = (const float4*)(P2w + (size_t)lo * RANK);
            const float4* p2hi = (const float4*)(P2w + (size_t)hi * RANK);
            float4 a0 = p2lo[0], a1 = p2lo[1];
            float4 b0 = p2hi[0], b1 = p2hi[1];
            float dlo = P2b[lo]
                      + hh[0]*a0.x + hh[1]*a0.y + hh[2]*a0.z + hh[3]*a0.w
                      + hh[4]*a1.x + hh[5]*a1.y + hh[6]*a1.z + hh[7]*a1.w;
            float dhi = P2b[hi]
                      + hh[0]*b0.x + hh[1]*b0.y + hh[2]*b0.z + hh[3]*b0.w
                      + hh[4]*b1.x + hh[5]*b1.y + hh[6]*b1.z + hh[7]*b1.w;
            float di = dlo + (dhi - dlo) * fr;
            float g  = fmaxf(bg + alpha * di, 0.0f);

            float zr = sre[k] * g;
            float zi = sim[k] * g;
            sre[k] = zr;
            sim[k] = zi;

#pragma unroll
            for (int r = 0; r < RANK; r++) {
                float u_ = Ur[r * S_LEN + k], v_ = Ui[r * S_LEN + k];
                pr[r]  += zr * u_ - zi * v_;
                pim[r] += zr * v_ + zi * u_;
                float w_ = Vr[r * S_LEN + k], y_ = Vi[r * S_LEN + k];
                qr[r]  += zr * w_ - zi * y_;
                qim[r] += zr * y_ + zi * w_;
            }
        }

#pragma unroll
        for (int r = 0; r < RANK; r++) {
#pragma unroll
            for (int off = 32; off > 0; off >>= 1) {
                pr[r]  += __shfl_xor(pr[r],  off, 64);
                pim[r] += __shfl_xor(pim[r], off, 64);
                qr[r]  += __shfl_xor(qr[r],  off, 64);
                qim[r] += __shfl_xor(qim[r], off, 64);
            }
        }
        if (lane == 0) {
#pragma unroll
            for (int r = 0; r < RANK; r++) {
                red[wid * 32 + r]      = pr[r];
                red[wid * 32 + 8 + r]  = pim[r];
                red[wid * 32 + 16 + r] = qr[r];
                red[wid * 32 + 24 + r] = qim[r];
            }
        }
        __syncthreads();
        if (t < 32) {
            float v = 0.0f;
#pragma unroll
            for (int w = 0; w < 8; w++) v += red[w * 32 + t];
            red[t] = v;
        }
        __syncthreads();
        if (t < RANK) {
            float prr = red[t],      pii = red[8 + t];
            float qrr = red[16 + t], qii = red[24 + t];
            gam[t]        = prr * qrr + pii * qii;  // Re(p * conj(q))
            gam[RANK + t] = pii * qrr - prr * qii;  // Im(p * conj(q))
        }
        __syncthreads();
    }

    // phase 4: z[k] += sum_r gamma[r] * (Wr[k,r] + i*Wi[k,r])
    {
        float gr[RANK], gi[RANK];
#pragma unroll
        for (int r = 0; r < RANK; r++) { gr[r] = gam[r]; gi[r] = gam[RANK + r]; }
        const float4* Wr4 = (const float4*)Wr;
        const float4* Wi4 = (const float4*)Wi;
        for (int i = 0; i < PER; i++) {
            int k = t + NT * i;
            float4 wa = Wr4[k * 2], wb = Wr4[k * 2 + 1];
            float4 va = Wi4[k * 2], vb = Wi4[k * 2 + 1];
            float wr_[RANK] = { wa.x, wa.y, wa.z, wa.w, wb.x, wb.y, wb.z, wb.w };
            float wi_[RANK] = { va.x, va.y, va.z, va.w, vb.x, vb.y, vb.z, vb.w };
            float ar = 0.f, ai = 0.f;
#pragma unroll
            for (int r = 0; r < RANK; r++) {
                ar += gr[r] * wr_[r] - gi[r] * wi_[r];
                ai += gr[r] * wi_[r] + gi[r] * wr_[r];
            }
            sre[k] += ar;
            sim[k] += ai;
        }
        __syncthreads();
    }

    // ================= inverse FFT: natural k in -> natural n out ==============
    {
        // round 1: read z linear, DFT over k4
#pragma unroll
        for (int c=0;c<8;c++){ ur[c] = sre[t + 512*c]; ui[c] = sim[t + 512*c]; }
        dft8<1>(ur, ui);
        __syncthreads();   // z consumed before A overwrites
        const int baseA = (t & 63) + 512 * (t >> 6);
#pragma unroll
        for (int e=0;e<8;e++){ sre[baseA + 64*e] = ur[e]; sim[baseA + 64*e] = ui[e]; }
    }
    __syncthreads();
    {
#pragma unroll
        for (int m=0;m<8;m++){ ur[m] = sre[t + 512*m]; ui[m] = sim[t + 512*m]; }
        twiddle8<1>(ur, ui, TWO_PI * (float)(t >> 6) * (1.0f/64.0f));
        dft8<1>(ur, ui);
        __syncthreads();
        const int baseB = (t & 7) + 8*(t >> 6) + 520*((t >> 3) & 7);
#pragma unroll
        for (int e=0;e<8;e++){ sre[baseB + 64*e] = ur[e]; sim[baseB + 64*e] = ui[e]; }
    }
    __syncthreads();
    {
#pragma unroll
        for (int m=0;m<8;m++){ ur[m] = sre[t + 520*m]; ui[m] = sim[t + 520*m]; }
        twiddle8<1>(ur, ui, TWO_PI * (float)(t >> 3) * (1.0f/512.0f));
        dft8<1>(ur, ui);
        __syncthreads();
        const int baseC = (t >> 3) + 520*(t & 7);
#pragma unroll
        for (int e=0;e<8;e++){ sre[baseC + 64*e] = ur[e]; sim[baseC + 64*e] = ui[e]; }
    }
    __syncthreads();
    {
#pragma unroll
        for (int m=0;m<8;m++){ ur[m] = sre[t + 520*m]; ui[m] = sim[t + 520*m]; }
        twiddle8<1>(ur, ui, TWO_PI * (float)t * (1.0f/4096.0f));
        dft8<1>(ur, ui);
        // write real part straight to global: out[n], n = t + 512*e (coalesced)
        float* orow = out + (size_t)row * S_LEN;
        const float scale = 1.0f / (float)S_LEN;
#pragma unroll
        for (int e=0;e<8;e++){
            orow[t + 512*e] = ur[e] * scale;
        }
    }
}

extern "C" void kernel_launch(void* const* d_in, const int* in_sizes, int n_in,
                              void* d_out, int out_size, void* d_ws, size_t ws_size,
                              hipStream_t stream) {
    const float* x    = (const float*)d_in[0];
    const float* Ur   = (const float*)d_in[1];
    const float* Ui   = (const float*)d_in[2];
    const float* Vr   = (const float*)d_in[3];
    const float* Vi   = (const float*)d_in[4];
    const float* Wr   = (const float*)d_in[5];
    const float* Wi   = (const float*)d_in[6];
    const float* P1w  = (const float*)d_in[7];
    const float* P1b  = (const float*)d_in[8];
    const float* P2w  = (const float*)d_in[9];
    const float* P2b  = (const float*)d_in[10];
    const float* alph = (const float*)d_in[11];

    recip_mixer<<<dim3(2048), dim3(NT), 0, stream>>>(
        x, Ur, Ui, Vr, Vi, Wr, Wi, P1w, P1b, P2w, P2b, alph, (float*)d_out);
}

// Round 3
// 262.198 us; speedup vs baseline: 1.5332x; 1.5332x over previous
//
#include <hip/hip_runtime.h>

#define S_LEN 4096
#define NT 512
#define PER 8
#define RANK 8
#define AP 4160   // padded LDS array size (max transpose addr 4151)
#define TWO_PI 6.2831853071795864769f

__device__ __forceinline__ void cmul(float& xr, float& xi, float cr, float ci){
    float tr = xr*cr - xi*ci;
    xi = xr*ci + xi*cr;
    xr = tr;
}

// 4-point DFT, in place. SIGN=-1 forward (W=e^{-i}), SIGN=+1 inverse.
// Natural-order outputs: slots (a,b,c,d) = X[0..3].
template<int SIGN>
__device__ __forceinline__ void dft4(float& ar,float& ai,float& br,float& bi,
                                     float& cr,float& ci,float& dr,float& di){
    float Ar=ar+cr, Ai=ai+ci;
    float Br=ar-cr, Bi=ai-ci;
    float Cr=br+dr, Ci=bi+di;
    float Dr, Di;
    if (SIGN < 0){ Dr = bi-di; Di = dr-br; }   // -i*(b-d)
    else         { Dr = di-bi; Di = br-dr; }   // +i*(b-d)
    ar=Ar+Cr; ai=Ai+Ci;
    br=Br+Dr; bi=Bi+Di;
    cr=Ar-Cr; ci=Ai-Ci;
    dr=Br-Dr; di=Bi-Di;
}

// 8-point DFT in registers, natural-order in AND out (even/odd radix-2 split).
template<int SIGN>
__device__ __forceinline__ void dft8(float ur[8], float ui[8]){
    const float h = 0.70710678118654752f;
    float er0=ur[0], ei0=ui[0], er1=ur[2], ei1=ui[2];
    float er2=ur[4], ei2=ui[4], er3=ur[6], ei3=ui[6];
    float fr0=ur[1], fi0=ui[1], fr1=ur[3], fi1=ui[3];
    float fr2=ur[5], fi2=ui[5], fr3=ur[7], fi3=ui[7];
    dft4<SIGN>(er0,ei0, er1,ei1, er2,ei2, er3,ei3);   // E = DFT4(x0,x2,x4,x6)
    dft4<SIGN>(fr0,fi0, fr1,fi1, fr2,fi2, fr3,fi3);   // O = DFT4(x1,x3,x5,x7)
    // O[k] *= W8^k
    {   const float c =  h, s_ = (SIGN<0) ? -h : h;
        cmul(fr1, fi1, c, s_); }
    {   float tr = fr2, ti = fi2;
        if (SIGN < 0){ fr2 =  ti; fi2 = -tr; }   // *(-i)
        else         { fr2 = -ti; fi2 =  tr; }   // *(+i)
    }
    {   const float c = -h, s_ = (SIGN<0) ? -h : h;
        cmul(fr3, fi3, c, s_); }
    ur[0]=er0+fr0; ui[0]=ei0+fi0;
    ur[1]=er1+fr1; ui[1]=ei1+fi1;
    ur[2]=er2+fr2; ui[2]=ei2+fi2;
    ur[3]=er3+fr3; ui[3]=ei3+fi3;
    ur[4]=er0-fr0; ui[4]=ei0-fi0;
    ur[5]=er1-fr1; ui[5]=ei1-fi1;
    ur[6]=er2-fr2; ui[6]=ei2-fi2;
    ur[7]=er3-fr3; ui[7]=ei3-fi3;
}

// multiply u[m] by exp(SIGN * i * theta * m), m = 0..7 (iterative powers)
template<int SIGN>
__device__ __forceinline__ void twiddle8(float ur[8], float ui[8], float theta){
    float s, c;
    __sincosf(theta, &s, &c);
    const float wi = (SIGN < 0) ? -s : s;
    const float wr = c;
    float pr = wr, pi = wi;      // w^1
    cmul(ur[1], ui[1], pr, pi);
#pragma unroll
    for (int m=2;m<8;m++){
        float nr = pr*wr - pi*wi;
        pi = pr*wi + pi*wr;
        pr = nr;
        cmul(ur[m], ui[m], pr, pi);
    }
}

// 4096 = 8*8*8*8, n = n1 + 8n2 + 64n3 + 512n4, k = e1 + 8e2 + 64e3 + 512e4.
// Round r DFTs over n_{5-r}; twiddles W_{8^r}^{digit * k_so_far}.
// LDS layouts are digit-reversed so every round's READ is linear:
//   A[n1+8n2 + 64e1 + 512n3]           (write: 2-way, free; read: t+512m)
//   B[n1 + 8e1 + 64e2 + 520n2]         (write: 2-way via pad 520; read: t+520m)
//   C[(e1+8e2) + 64e3 + 520n1]         (write: 2-way via pad 520; read: t+520m)
//   z linear [t + 512e4]
//
// __launch_bounds__(512, 4): cap VGPR at 128 — do NOT force 64 (the ",8" variant
// made the compiler crush to 32 VGPR + scratch spills: FETCH 24->382 MB, 330us).
// Occupancy is LDS-limited anyway: 34816 B -> 4 blocks/CU x 8 waves = 32 waves = 100%,
// provided natural VGPR count stays <= 64.

__global__ __launch_bounds__(NT, 4) void recip_mixer(
    const float* __restrict__ x,
    const float* __restrict__ Ur, const float* __restrict__ Ui,
    const float* __restrict__ Vr, const float* __restrict__ Vi,
    const float* __restrict__ Wr, const float* __restrict__ Wi,
    const float* __restrict__ P1w, const float* __restrict__ P1b,
    const float* __restrict__ P2w, const float* __restrict__ P2b,
    const float* __restrict__ alphap,
    float* __restrict__ out)
{
    __shared__ float sre[AP], sim[AP];
    __shared__ float red[256];
    __shared__ float hid[RANK];
    __shared__ float gam[2 * RANK];

    const int t    = threadIdx.x;
    const int row  = blockIdx.x;
    const int lane = t & 63;
    const int wid  = t >> 6;

    float ur[8], ui[8];

    // ================= forward FFT: natural in -> natural k out =================
    {
        // round 1: t = n1+8n2+64n3; DFT over n4 (global reads coalesced)
        const float* xrow = x + (size_t)row * S_LEN;
#pragma unroll
        for (int c=0;c<8;c++){ ur[c] = xrow[t + 512*c]; ui[c] = 0.0f; }
        dft8<-1>(ur, ui);
        const int baseA = (t & 63) + 512 * (t >> 6);
#pragma unroll
        for (int e=0;e<8;e++){ sre[baseA + 64*e] = ur[e]; sim[baseA + 64*e] = ui[e]; }
    }
    __syncthreads();
    {
        // round 2: t = (n1+8n2) + 64e1; read A linear, twiddle W_64^{n3 e1}, DFT over n3
#pragma unroll
        for (int m=0;m<8;m++){ ur[m] = sre[t + 512*m]; ui[m] = sim[t + 512*m]; }
        twiddle8<-1>(ur, ui, TWO_PI * (float)(t >> 6) * (1.0f/64.0f));
        dft8<-1>(ur, ui);
        __syncthreads();   // all of A consumed before B overwrites
        const int baseB = (t & 7) + 8*(t >> 6) + 520*((t >> 3) & 7);
#pragma unroll
        for (int e=0;e<8;e++){ sre[baseB + 64*e] = ur[e]; sim[baseB + 64*e] = ui[e]; }
    }
    __syncthreads();
    {
        // round 3: t = n1 + 8e1 + 64e2; read B linear, twiddle W_512^{n2 (e1+8e2)}, DFT over n2
#pragma unroll
        for (int m=0;m<8;m++){ ur[m] = sre[t + 520*m]; ui[m] = sim[t + 520*m]; }
        twiddle8<-1>(ur, ui, TWO_PI * (float)(t >> 3) * (1.0f/512.0f));
        dft8<-1>(ur, ui);
        __syncthreads();   // B consumed before C overwrites
        const int baseC = (t >> 3) + 520*(t & 7);
#pragma unroll
        for (int e=0;e<8;e++){ sre[baseC + 64*e] = ur[e]; sim[baseC + 64*e] = ui[e]; }
    }
    __syncthreads();
    {
        // round 4: t = e1+8e2+64e3 = k mod 512; read C linear, twiddle W_4096^{n1 t}, DFT over n1
#pragma unroll
        for (int m=0;m<8;m++){ ur[m] = sre[t + 520*m]; ui[m] = sim[t + 520*m]; }
        twiddle8<-1>(ur, ui, TWO_PI * (float)t * (1.0f/4096.0f));
        dft8<-1>(ur, ui);
        __syncthreads();   // C consumed before z overwrites
        // write spectrum linear: z[t + 512*e4]
#pragma unroll
        for (int e=0;e<8;e++){ sre[t + 512*e] = ur[e]; sim[t + 512*e] = ui[e]; }
    }
    __syncthreads();

    // ================= middle phase (z in sre/sim linear) =====
    // phase 1: hidden = relu(P1w @ [Re z ; Im z] + P1b)
    {
        float h[RANK];
#pragma unroll
        for (int r = 0; r < RANK; r++) h[r] = 0.0f;
        for (int i = 0; i < PER; i++) {
            int k = t + NT * i;
            float zr = sre[k], zi = sim[k];
#pragma unroll
            for (int r = 0; r < RANK; r++) {
                h[r] += zr * P1w[r * (2 * S_LEN) + k]
                      + zi * P1w[r * (2 * S_LEN) + S_LEN + k];
            }
        }
#pragma unroll
        for (int r = 0; r < RANK; r++) {
#pragma unroll
            for (int off = 32; off > 0; off >>= 1)
                h[r] += __shfl_xor(h[r], off, 64);
        }
        if (lane == 0) {
#pragma unroll
            for (int r = 0; r < RANK; r++) red[wid * RANK + r] = h[r];
        }
        __syncthreads();
        if (t < RANK) {
            float v = 0.0f;
#pragma unroll
            for (int w = 0; w < 8; w++) v += red[w * RANK + t];
            hid[t] = fmaxf(v + P1b[t], 0.0f);
        }
        __syncthreads();
    }

    // phase 2+3: per-k gain, scale z, accumulate p/q rank-8 partials
    {
        float hh[RANK];
#pragma unroll
        for (int r = 0; r < RANK; r++) hh[r] = hid[r];
        const float alpha = alphap[0];

        float pr[RANK], pim[RANK], qr[RANK], qim[RANK];
#pragma unroll
        for (int r = 0; r < RANK; r++) { pr[r]=0.f; pim[r]=0.f; qr[r]=0.f; qim[r]=0.f; }

        for (int i = 0; i < PER; i++) {
            int k = t + NT * i;
            int m = (k < S_LEN - k) ? k : (S_LEN - k);
            float nf = (float)(2 * m) * (1.0f / (float)S_LEN);
            float tt = nf * 5.0f;
            float lb = __expf(-0.5f * tt * tt);
            float hd = 0.5f / (1.0f + __expf(-(nf - 0.6f) * 10.0f));
            float bg = fmaxf(1.0f + lb - hd, 0.0f);

            float scaled = nf * 4095.0f;
            float fl  = floorf(scaled);
            int   lo  = (int)fl;
            int   hi  = (int)ceilf(scaled);
            float fr  = scaled - fl;

            const float4* p2lo = (const float4*)(P2w + (size_t)lo * RANK);
            const float4* p2hi = (const float4*)(P2w + (size_t)hi * RANK);
            float4 a0 = p2lo[0], a1 = p2lo[1];
            float4 b0 = p2hi[0], b1 = p2hi[1];
            float dlo = P2b[lo]
                      + hh[0]*a0.x + hh[1]*a0.y + hh[2]*a0.z + hh[3]*a0.w
                      + hh[4]*a1.x + hh[5]*a1.y + hh[6]*a1.z + hh[7]*a1.w;
            float dhi = P2b[hi]
                      + hh[0]*b0.x + hh[1]*b0.y + hh[2]*b0.z + hh[3]*b0.w
                      + hh[4]*b1.x + hh[5]*b1.y + hh[6]*b1.z + hh[7]*b1.w;
            float di = dlo + (dhi - dlo) * fr;
            float g  = fmaxf(bg + alpha * di, 0.0f);

            float zr = sre[k] * g;
            float zi = sim[k] * g;
            sre[k] = zr;
            sim[k] = zi;

#pragma unroll
            for (int r = 0; r < RANK; r++) {
                float u_ = Ur[r * S_LEN + k], v_ = Ui[r * S_LEN + k];
                pr[r]  += zr * u_ - zi * v_;
                pim[r] += zr * v_ + zi * u_;
                float w_ = Vr[r * S_LEN + k], y_ = Vi[r * S_LEN + k];
                qr[r]  += zr * w_ - zi * y_;
                qim[r] += zr * y_ + zi * w_;
            }
        }

#pragma unroll
        for (int r = 0; r < RANK; r++) {
#pragma unroll
            for (int off = 32; off > 0; off >>= 1) {
                pr[r]  += __shfl_xor(pr[r],  off, 64);
                pim[r] += __shfl_xor(pim[r], off, 64);
                qr[r]  += __shfl_xor(qr[r],  off, 64);
                qim[r] += __shfl_xor(qim[r], off, 64);
            }
        }
        if (lane == 0) {
#pragma unroll
            for (int r = 0; r < RANK; r++) {
                red[wid * 32 + r]      = pr[r];
                red[wid * 32 + 8 + r]  = pim[r];
                red[wid * 32 + 16 + r] = qr[r];
                red[wid * 32 + 24 + r] = qim[r];
            }
        }
        __syncthreads();
        if (t < 32) {
            float v = 0.0f;
#pragma unroll
            for (int w = 0; w < 8; w++) v += red[w * 32 + t];
            red[t] = v;
        }
        __syncthreads();
        if (t < RANK) {
            float prr = red[t],      pii = red[8 + t];
            float qrr = red[16 + t], qii = red[24 + t];
            gam[t]        = prr * qrr + pii * qii;  // Re(p * conj(q))
            gam[RANK + t] = pii * qrr - prr * qii;  // Im(p * conj(q))
        }
        __syncthreads();
    }

    // phase 4: z[k] += sum_r gamma[r] * (Wr[k,r] + i*Wi[k,r])
    {
        float gr[RANK], gi[RANK];
#pragma unroll
        for (int r = 0; r < RANK; r++) { gr[r] = gam[r]; gi[r] = gam[RANK + r]; }
        const float4* Wr4 = (const float4*)Wr;
        const float4* Wi4 = (const float4*)Wi;
        for (int i = 0; i < PER; i++) {
            int k = t + NT * i;
            float4 wa = Wr4[k * 2], wb = Wr4[k * 2 + 1];
            float4 va = Wi4[k * 2], vb = Wi4[k * 2 + 1];
            float wr_[RANK] = { wa.x, wa.y, wa.z, wa.w, wb.x, wb.y, wb.z, wb.w };
            float wi_[RANK] = { va.x, va.y, va.z, va.w, vb.x, vb.y, vb.z, vb.w };
            float ar = 0.f, ai = 0.f;
#pragma unroll
            for (int r = 0; r < RANK; r++) {
                ar += gr[r] * wr_[r] - gi[r] * wi_[r];
                ai += gr[r] * wi_[r] + gi[r] * wr_[r];
            }
            sre[k] += ar;
            sim[k] += ai;
        }
        __syncthreads();
    }

    // ================= inverse FFT: natural k in -> natural n out ==============
    {
        // round 1: read z linear, DFT over k4
#pragma unroll
        for (int c=0;c<8;c++){ ur[c] = sre[t + 512*c]; ui[c] = sim[t + 512*c]; }
        dft8<1>(ur, ui);
        __syncthreads();   // z consumed before A overwrites
        const int baseA = (t & 63) + 512 * (t >> 6);
#pragma unroll
        for (int e=0;e<8;e++){ sre[baseA + 64*e] = ur[e]; sim[baseA + 64*e] = ui[e]; }
    }
    __syncthreads();
    {
#pragma unroll
        for (int m=0;m<8;m++){ ur[m] = sre[t + 512*m]; ui[m] = sim[t + 512*m]; }
        twiddle8<1>(ur, ui, TWO_PI * (float)(t >> 6) * (1.0f/64.0f));
        dft8<1>(ur, ui);
        __syncthreads();
        const int baseB = (t & 7) + 8*(t >> 6) + 520*((t >> 3) & 7);
#pragma unroll
        for (int e=0;e<8;e++){ sre[baseB + 64*e] = ur[e]; sim[baseB + 64*e] = ui[e]; }
    }
    __syncthreads();
    {
#pragma unroll
        for (int m=0;m<8;m++){ ur[m] = sre[t + 520*m]; ui[m] = sim[t + 520*m]; }
        twiddle8<1>(ur, ui, TWO_PI * (float)(t >> 3) * (1.0f/512.0f));
        dft8<1>(ur, ui);
        __syncthreads();
        const int baseC = (t >> 3) + 520*(t & 7);
#pragma unroll
        for (int e=0;e<8;e++){ sre[baseC + 64*e] = ur[e]; sim[baseC + 64*e] = ui[e]; }
    }
    __syncthreads();
    {
#pragma unroll
        for (int m=0;m<8;m++){ ur[m] = sre[t + 520*m]; ui[m] = sim[t + 520*m]; }
        twiddle8<1>(ur, ui, TWO_PI * (float)t * (1.0f/4096.0f));
        dft8<1>(ur, ui);
        // write real part straight to global: out[n], n = t + 512*e (coalesced)
        float* orow = out + (size_t)row * S_LEN;
        const float scale = 1.0f / (float)S_LEN;
#pragma unroll
        for (int e=0;e<8;e++){
            orow[t + 512*e] = ur[e] * scale;
        }
    }
}

extern "C" void kernel_launch(void* const* d_in, const int* in_sizes, int n_in,
                              void* d_out, int out_size, void* d_ws, size_t ws_size,
                              hipStream_t stream) {
    const float* x    = (const float*)d_in[0];
    const float* Ur   = (const float*)d_in[1];
    const float* Ui   = (const float*)d_in[2];
    const float* Vr   = (const float*)d_in[3];
    const float* Vi   = (const float*)d_in[4];
    const float* Wr   = (const float*)d_in[5];
    const float* Wi   = (const float*)d_in[6];
    const float* P1w  = (const float*)d_in[7];
    const float* P1b  = (const float*)d_in[8];
    const float* P2w  = (const float*)d_in[9];
    const float* P2b  = (const float*)d_in[10];
    const float* alph = (const float*)d_in[11];

    recip_mixer<<<dim3(2048), dim3(NT), 0, stream>>>(
        x, Ur, Ui, Vr, Vi, Wr, Wi, P1w, P1b, P2w, P2b, alph, (float*)d_out);
}

// Round 4
// 246.140 us; speedup vs baseline: 1.6332x; 1.0652x over previous
//
#include <hip/hip_runtime.h>

#define S_LEN 4096
#define NT 512
#define PER 8
#define RANK 8
#define AP 4160   // padded LDS array size (max transpose addr 4151)
#define TWO_PI 6.2831853071795864769f

__device__ __forceinline__ void cmul(float& xr, float& xi, float cr, float ci){
    float tr = xr*cr - xi*ci;
    xi = xr*ci + xi*cr;
    xr = tr;
}

// 4-point DFT, in place. SIGN=-1 forward (W=e^{-i}), SIGN=+1 inverse.
template<int SIGN>
__device__ __forceinline__ void dft4(float& ar,float& ai,float& br,float& bi,
                                     float& cr,float& ci,float& dr,float& di){
    float Ar=ar+cr, Ai=ai+ci;
    float Br=ar-cr, Bi=ai-ci;
    float Cr=br+dr, Ci=bi+di;
    float Dr, Di;
    if (SIGN < 0){ Dr = bi-di; Di = dr-br; }   // -i*(b-d)
    else         { Dr = di-bi; Di = br-dr; }   // +i*(b-d)
    ar=Ar+Cr; ai=Ai+Ci;
    br=Br+Dr; bi=Bi+Di;
    cr=Ar-Cr; ci=Ai-Ci;
    dr=Br-Dr; di=Bi-Di;
}

// 8-point DFT in registers, natural-order in AND out (even/odd radix-2 split).
template<int SIGN>
__device__ __forceinline__ void dft8(float ur[8], float ui[8]){
    const float h = 0.70710678118654752f;
    float er0=ur[0], ei0=ui[0], er1=ur[2], ei1=ui[2];
    float er2=ur[4], ei2=ui[4], er3=ur[6], ei3=ui[6];
    float fr0=ur[1], fi0=ui[1], fr1=ur[3], fi1=ui[3];
    float fr2=ur[5], fi2=ui[5], fr3=ur[7], fi3=ui[7];
    dft4<SIGN>(er0,ei0, er1,ei1, er2,ei2, er3,ei3);   // E = DFT4(x0,x2,x4,x6)
    dft4<SIGN>(fr0,fi0, fr1,fi1, fr2,fi2, fr3,fi3);   // O = DFT4(x1,x3,x5,x7)
    // O[k] *= W8^k
    {   const float c =  h, s_ = (SIGN<0) ? -h : h;
        cmul(fr1, fi1, c, s_); }
    {   float tr = fr2, ti = fi2;
        if (SIGN < 0){ fr2 =  ti; fi2 = -tr; }   // *(-i)
        else         { fr2 = -ti; fi2 =  tr; }   // *(+i)
    }
    {   const float c = -h, s_ = (SIGN<0) ? -h : h;
        cmul(fr3, fi3, c, s_); }
    ur[0]=er0+fr0; ui[0]=ei0+fi0;
    ur[1]=er1+fr1; ui[1]=ei1+fi1;
    ur[2]=er2+fr2; ui[2]=ei2+fi2;
    ur[3]=er3+fr3; ui[3]=ei3+fi3;
    ur[4]=er0-fr0; ui[4]=ei0-fi0;
    ur[5]=er1-fr1; ui[5]=ei1-fi1;
    ur[6]=er2-fr2; ui[6]=ei2-fi2;
    ur[7]=er3-fr3; ui[7]=ei3-fi3;
}

// multiply u[m] by exp(SIGN * i * theta * m), m = 0..7 (iterative powers)
template<int SIGN>
__device__ __forceinline__ void twiddle8(float ur[8], float ui[8], float theta){
    float s, c;
    __sincosf(theta, &s, &c);
    const float wi = (SIGN < 0) ? -s : s;
    const float wr = c;
    float pr = wr, pi = wi;      // w^1
    cmul(ur[1], ui[1], pr, pi);
#pragma unroll
    for (int m=2;m<8;m++){
        float nr = pr*wr - pi*wi;
        pi = pr*wi + pi*wr;
        pr = nr;
        cmul(ur[m], ui[m], pr, pi);
    }
}

// 4096 = 8*8*8*8, n = n1 + 8n2 + 64n3 + 512n4, k = e1 + 8e2 + 64e3 + 512e4.
// Round r DFTs over n_{5-r}; twiddles W_{8^r}^{digit * k_so_far}.
// LDS layouts are digit-reversed so every round's READ is linear:
//   A[n1+8n2 + 64e1 + 512n3]           (write: 2-way, free; read: t+512m)
//   B[n1 + 8e1 + 64e2 + 520n2]         (write: 2-way via pad 520; read: t+520m)
//   C[(e1+8e2) + 64e3 + 520n1]         (write: 2-way via pad 520; read: t+520m)
//   z linear [t + 512e4]
//
// VGPR discipline (measured r0-r3): waves/CU HALVE at VGPR=64 (m69 cliff).
//   VGPR=64 -> 43% occupancy; VGPR=32 -> 83%. The 64-reg peak was the fused
//   gain+p+q middle loop (8 hh + 32 accum + 16 float4 + temps). Split into
//   pass A (gain+scale, ~34 peak) and pass B (p/q accum, ~46 peak) to land
//   kernel-wide <= ~56. launch_bounds(512,4) caps at 128 (no forced crush —
//   the ",8" variant collapsed to 32 VGPR + 780 MB spill traffic, 330 us).

__global__ __launch_bounds__(NT, 4) void recip_mixer(
    const float* __restrict__ x,
    const float* __restrict__ Ur, const float* __restrict__ Ui,
    const float* __restrict__ Vr, const float* __restrict__ Vi,
    const float* __restrict__ Wr, const float* __restrict__ Wi,
    const float* __restrict__ P1w, const float* __restrict__ P1b,
    const float* __restrict__ P2w, const float* __restrict__ P2b,
    const float* __restrict__ alphap,
    float* __restrict__ out)
{
    __shared__ float sre[AP], sim[AP];
    __shared__ float red[256];
    __shared__ float hid[RANK];
    __shared__ float gam[2 * RANK];

    const int t    = threadIdx.x;
    const int row  = blockIdx.x;
    const int lane = t & 63;
    const int wid  = t >> 6;

    float ur[8], ui[8];

    // ================= forward FFT: natural in -> natural k out =================
    {
        // round 1: t = n1+8n2+64n3; DFT over n4 (global reads coalesced)
        const float* xrow = x + (size_t)row * S_LEN;
#pragma unroll
        for (int c=0;c<8;c++){ ur[c] = xrow[t + 512*c]; ui[c] = 0.0f; }
        dft8<-1>(ur, ui);
        const int baseA = (t & 63) + 512 * (t >> 6);
#pragma unroll
        for (int e=0;e<8;e++){ sre[baseA + 64*e] = ur[e]; sim[baseA + 64*e] = ui[e]; }
    }
    __syncthreads();
    {
        // round 2: t = (n1+8n2) + 64e1; read A linear, twiddle W_64^{n3 e1}, DFT over n3
#pragma unroll
        for (int m=0;m<8;m++){ ur[m] = sre[t + 512*m]; ui[m] = sim[t + 512*m]; }
        twiddle8<-1>(ur, ui, TWO_PI * (float)(t >> 6) * (1.0f/64.0f));
        dft8<-1>(ur, ui);
        __syncthreads();   // all of A consumed before B overwrites
        const int baseB = (t & 7) + 8*(t >> 6) + 520*((t >> 3) & 7);
#pragma unroll
        for (int e=0;e<8;e++){ sre[baseB + 64*e] = ur[e]; sim[baseB + 64*e] = ui[e]; }
    }
    __syncthreads();
    {
        // round 3: t = n1 + 8e1 + 64e2; read B linear, twiddle W_512^{n2 (e1+8e2)}, DFT over n2
#pragma unroll
        for (int m=0;m<8;m++){ ur[m] = sre[t + 520*m]; ui[m] = sim[t + 520*m]; }
        twiddle8<-1>(ur, ui, TWO_PI * (float)(t >> 3) * (1.0f/512.0f));
        dft8<-1>(ur, ui);
        __syncthreads();   // B consumed before C overwrites
        const int baseC = (t >> 3) + 520*(t & 7);
#pragma unroll
        for (int e=0;e<8;e++){ sre[baseC + 64*e] = ur[e]; sim[baseC + 64*e] = ui[e]; }
    }
    __syncthreads();
    {
        // round 4: t = e1+8e2+64e3 = k mod 512; read C linear, twiddle W_4096^{n1 t}, DFT over n1
#pragma unroll
        for (int m=0;m<8;m++){ ur[m] = sre[t + 520*m]; ui[m] = sim[t + 520*m]; }
        twiddle8<-1>(ur, ui, TWO_PI * (float)t * (1.0f/4096.0f));
        dft8<-1>(ur, ui);
        __syncthreads();   // C consumed before z overwrites
        // write spectrum linear: z[t + 512*e4]
#pragma unroll
        for (int e=0;e<8;e++){ sre[t + 512*e] = ur[e]; sim[t + 512*e] = ui[e]; }
    }
    __syncthreads();

    // ================= middle phase (z in sre/sim linear) =====
    // phase 1: hidden = relu(P1w @ [Re z ; Im z] + P1b)
    {
        float h[RANK];
#pragma unroll
        for (int r = 0; r < RANK; r++) h[r] = 0.0f;
        for (int i = 0; i < PER; i++) {
            int k = t + NT * i;
            float zr = sre[k], zi = sim[k];
#pragma unroll
            for (int r = 0; r < RANK; r++) {
                h[r] += zr * P1w[r * (2 * S_LEN) + k]
                      + zi * P1w[r * (2 * S_LEN) + S_LEN + k];
            }
        }
#pragma unroll
        for (int r = 0; r < RANK; r++) {
#pragma unroll
            for (int off = 32; off > 0; off >>= 1)
                h[r] += __shfl_xor(h[r], off, 64);
        }
        if (lane == 0) {
#pragma unroll
            for (int r = 0; r < RANK; r++) red[wid * RANK + r] = h[r];
        }
        __syncthreads();
        if (t < RANK) {
            float v = 0.0f;
#pragma unroll
            for (int w = 0; w < 8; w++) v += red[w * RANK + t];
            hid[t] = fmaxf(v + P1b[t], 0.0f);
        }
        __syncthreads();
    }

    // phase 2a: per-k gain, scale z in LDS. NO accumulators live here —
    // this pass peaks at ~34 VGPR (hh[8] + gain temps). Each thread touches
    // only its own k slots, so no barrier needed before pass 2b.
    {
        float hh[RANK];
#pragma unroll
        for (int r = 0; r < RANK; r++) hh[r] = hid[r];
        const float alpha = alphap[0];

        for (int i = 0; i < PER; i++) {
            int k = t + NT * i;
            int m = (k < S_LEN - k) ? k : (S_LEN - k);
            float nf = (float)(2 * m) * (1.0f / (float)S_LEN);
            float tt = nf * 5.0f;
            float lb = __expf(-0.5f * tt * tt);
            float hd = 0.5f / (1.0f + __expf(-(nf - 0.6f) * 10.0f));
            float bg = fmaxf(1.0f + lb - hd, 0.0f);

            float scaled = nf * 4095.0f;
            float fl  = floorf(scaled);
            int   lo  = (int)fl;
            int   hi  = (int)ceilf(scaled);
            float fr  = scaled - fl;

            const float4* p2lo = (const float4*)(P2w + (size_t)lo * RANK);
            const float4* p2hi = (const float4*)(P2w + (size_t)hi * RANK);
            float4 a0 = p2lo[0], a1 = p2lo[1];
            float4 b0 = p2hi[0], b1 = p2hi[1];
            float dlo = P2b[lo]
                      + hh[0]*a0.x + hh[1]*a0.y + hh[2]*a0.z + hh[3]*a0.w
                      + hh[4]*a1.x + hh[5]*a1.y + hh[6]*a1.z + hh[7]*a1.w;
            float dhi = P2b[hi]
                      + hh[0]*b0.x + hh[1]*b0.y + hh[2]*b0.z + hh[3]*b0.w
                      + hh[4]*b1.x + hh[5]*b1.y + hh[6]*b1.z + hh[7]*b1.w;
            float di = dlo + (dhi - dlo) * fr;
            float g  = fmaxf(bg + alpha * di, 0.0f);

            sre[k] *= g;
            sim[k] *= g;
        }
    }
    // keep pass-B loads from being hoisted into pass A (would re-inflate VGPR peak)
    __builtin_amdgcn_sched_barrier(0);

    // phase 2b: accumulate p/q rank-8 partials from scaled z (~46 VGPR peak)
    {
        float pr[RANK], pim[RANK], qr[RANK], qim[RANK];
#pragma unroll
        for (int r = 0; r < RANK; r++) { pr[r]=0.f; pim[r]=0.f; qr[r]=0.f; qim[r]=0.f; }

        for (int i = 0; i < PER; i++) {
            int k = t + NT * i;
            float zr = sre[k];
            float zi = sim[k];
#pragma unroll
            for (int r = 0; r < RANK; r++) {
                float u_ = Ur[r * S_LEN + k], v_ = Ui[r * S_LEN + k];
                pr[r]  += zr * u_ - zi * v_;
                pim[r] += zr * v_ + zi * u_;
                float w_ = Vr[r * S_LEN + k], y_ = Vi[r * S_LEN + k];
                qr[r]  += zr * w_ - zi * y_;
                qim[r] += zr * y_ + zi * w_;
            }
        }

#pragma unroll
        for (int r = 0; r < RANK; r++) {
#pragma unroll
            for (int off = 32; off > 0; off >>= 1) {
                pr[r]  += __shfl_xor(pr[r],  off, 64);
                pim[r] += __shfl_xor(pim[r], off, 64);
                qr[r]  += __shfl_xor(qr[r],  off, 64);
                qim[r] += __shfl_xor(qim[r], off, 64);
            }
        }
        if (lane == 0) {
#pragma unroll
            for (int r = 0; r < RANK; r++) {
                red[wid * 32 + r]      = pr[r];
                red[wid * 32 + 8 + r]  = pim[r];
                red[wid * 32 + 16 + r] = qr[r];
                red[wid * 32 + 24 + r] = qim[r];
            }
        }
        __syncthreads();
        if (t < 32) {
            float v = 0.0f;
#pragma unroll
            for (int w = 0; w < 8; w++) v += red[w * 32 + t];
            red[t] = v;
        }
        __syncthreads();
        if (t < RANK) {
            float prr = red[t],      pii = red[8 + t];
            float qrr = red[16 + t], qii = red[24 + t];
            gam[t]        = prr * qrr + pii * qii;  // Re(p * conj(q))
            gam[RANK + t] = pii * qrr - prr * qii;  // Im(p * conj(q))
        }
        __syncthreads();
    }

    // phase 4: z[k] += sum_r gamma[r] * (Wr[k,r] + i*Wi[k,r])
    {
        float gr[RANK], gi[RANK];
#pragma unroll
        for (int r = 0; r < RANK; r++) { gr[r] = gam[r]; gi[r] = gam[RANK + r]; }
        const float4* Wr4 = (const float4*)Wr;
        const float4* Wi4 = (const float4*)Wi;
        for (int i = 0; i < PER; i++) {
            int k = t + NT * i;
            float4 wa = Wr4[k * 2], wb = Wr4[k * 2 + 1];
            float4 va = Wi4[k * 2], vb = Wi4[k * 2 + 1];
            float wr_[RANK] = { wa.x, wa.y, wa.z, wa.w, wb.x, wb.y, wb.z, wb.w };
            float wi_[RANK] = { va.x, va.y, va.z, va.w, vb.x, vb.y, vb.z, vb.w };
            float ar = 0.f, ai = 0.f;
#pragma unroll
            for (int r = 0; r < RANK; r++) {
                ar += gr[r] * wr_[r] - gi[r] * wi_[r];
                ai += gr[r] * wi_[r] + gi[r] * wr_[r];
            }
            sre[k] += ar;
            sim[k] += ai;
        }
        __syncthreads();
    }

    // ================= inverse FFT: natural k in -> natural n out ==============
    {
        // round 1: read z linear, DFT over k4
#pragma unroll
        for (int c=0;c<8;c++){ ur[c] = sre[t + 512*c]; ui[c] = sim[t + 512*c]; }
        dft8<1>(ur, ui);
        __syncthreads();   // z consumed before A overwrites
        const int baseA = (t & 63) + 512 * (t >> 6);
#pragma unroll
        for (int e=0;e<8;e++){ sre[baseA + 64*e] = ur[e]; sim[baseA + 64*e] = ui[e]; }
    }
    __syncthreads();
    {
#pragma unroll
        for (int m=0;m<8;m++){ ur[m] = sre[t + 512*m]; ui[m] = sim[t + 512*m]; }
        twiddle8<1>(ur, ui, TWO_PI * (float)(t >> 6) * (1.0f/64.0f));
        dft8<1>(ur, ui);
        __syncthreads();
        const int baseB = (t & 7) + 8*(t >> 6) + 520*((t >> 3) & 7);
#pragma unroll
        for (int e=0;e<8;e++){ sre[baseB + 64*e] = ur[e]; sim[baseB + 64*e] = ui[e]; }
    }
    __syncthreads();
    {
#pragma unroll
        for (int m=0;m<8;m++){ ur[m] = sre[t + 520*m]; ui[m] = sim[t + 520*m]; }
        twiddle8<1>(ur, ui, TWO_PI * (float)(t >> 3) * (1.0f/512.0f));
        dft8<1>(ur, ui);
        __syncthreads();
        const int baseC = (t >> 3) + 520*(t & 7);
#pragma unroll
        for (int e=0;e<8;e++){ sre[baseC + 64*e] = ur[e]; sim[baseC + 64*e] = ui[e]; }
    }
    __syncthreads();
    {
#pragma unroll
        for (int m=0;m<8;m++){ ur[m] = sre[t + 520*m]; ui[m] = sim[t + 520*m]; }
        twiddle8<1>(ur, ui, TWO_PI * (float)t * (1.0f/4096.0f));
        dft8<1>(ur, ui);
        // write real part straight to global: out[n], n = t + 512*e (coalesced)
        float* orow = out + (size_t)row * S_LEN;
        const float scale = 1.0f / (float)S_LEN;
#pragma unroll
        for (int e=0;e<8;e++){
            orow[t + 512*e] = ur[e] * scale;
        }
    }
}

extern "C" void kernel_launch(void* const* d_in, const int* in_sizes, int n_in,
                              void* d_out, int out_size, void* d_ws, size_t ws_size,
                              hipStream_t stream) {
    const float* x    = (const float*)d_in[0];
    const float* Ur   = (const float*)d_in[1];
    const float* Ui   = (const float*)d_in[2];
    const float* Vr   = (const float*)d_in[3];
    const float* Vi   = (const float*)d_in[4];
    const float* Wr   = (const float*)d_in[5];
    const float* Wi   = (const float*)d_in[6];
    const float* P1w  = (const float*)d_in[7];
    const float* P1b  = (const float*)d_in[8];
    const float* P2w  = (const float*)d_in[9];
    const float* P2b  = (const float*)d_in[10];
    const float* alph = (const float*)d_in[11];

    recip_mixer<<<dim3(2048), dim3(NT), 0, stream>>>(
        x, Ur, Ui, Vr, Vi, Wr, Wi, P1w, P1b, P2w, P2b, alph, (float*)d_out);
}